// Round 16
// baseline (418.149 us; speedup 1.0000x reference)
//
#include <hip/hip_runtime.h>

// LSTM, B=128, T=256 (255 steps), H=512, V=128, C=128.  OUTPUT = FLOAT32.
// 8 groups x 16 batch rows; 32 WGs/group; WG w owns h-cols [16w,16w+16).
// Wave v (of 4) = K-slice ks in [4v,4v+4) for ALL 4 gates.
// Round 16 (step micro-opts; sync protocol unchanged from r15):
//  1) MFMA accumulator split: 8 independent 6-deep chains (was 4x12-deep)
//     -> dependent-latency ~halved.
//  2) plane-separated h exchange (2 u32 planes): consumer loads are 8x
//     dwordx4 directly into short8 operands (no u64 lo/hi repack), one
//     voffset + immediate offsets (minimal address VALU).
//  3) gate-vectorized partials part[..][row][col][gate]: 4x ds_write_b128 /
//     4x ds_read_b128 per thread (was 16x b32 each way).
// Sync: per-wave 8-producer scalar poll (s_dcache_inv + s_load_dwordx8,
// XCD-L2); WG tag by last of 4 waves; agent B-tags + bounded fallback.

typedef __attribute__((ext_vector_type(8))) short short8;
typedef __attribute__((ext_vector_type(4))) float f32x4;
typedef __attribute__((ext_vector_type(8))) unsigned int u32x8;
typedef __attribute__((ext_vector_type(16))) unsigned int u32x16;

#define NGROUPS 8
#define WGS_PER_GROUP 32
#define HDIM 512
#define TT 256
#define NSTEPS 255
#define CDIM 128
#define PGW 8192          // u32 words per (parity,group): 2 planes x 4096
#define PLANE_W 4096
#define TAGB_OFF 1024     // u32 offset of fallback tag region

__device__ unsigned int g_hbuf[4 * NGROUPS * PGW];   // 1 MB, 4 parities
__device__ unsigned int g_sync[TAGB_OFF + NGROUPS * WGS_PER_GROUP * 16];

static __device__ __forceinline__ unsigned short f32_to_bf16(float f) {
  unsigned int u = __builtin_bit_cast(unsigned int, f);
  u += 0x7fffu + ((u >> 16) & 1u);   // RNE
  return (unsigned short)(u >> 16);
}
static __device__ __forceinline__ float bf16_to_f32(unsigned short s) {
  unsigned int u = ((unsigned int)s) << 16;
  return __builtin_bit_cast(float, u);
}
static __device__ __forceinline__ float fast_sigmoid(float v) {
  return __builtin_amdgcn_rcpf(1.0f + __expf(-v));
}
static __device__ __forceinline__ float fast_tanh(float v) {
  return 1.0f - 2.0f * __builtin_amdgcn_rcpf(1.0f + __expf(2.0f * v));
}
static __device__ __forceinline__ const unsigned int* sgpr_ptr(const unsigned int* p) {
  const unsigned long long u = (unsigned long long)p;
  const unsigned int lo = __builtin_amdgcn_readfirstlane((unsigned int)u);
  const unsigned int hi = __builtin_amdgcn_readfirstlane((unsigned int)(u >> 32));
  return (const unsigned int*)(((unsigned long long)hi << 32) | (unsigned long long)lo);
}

static __device__ __forceinline__ unsigned int poll_min8(const unsigned int* p) {
  u32x8 A;
  asm volatile("s_dcache_inv\n\t"
               "s_load_dwordx8 %0, %1, 0x0\n\t"
               "s_waitcnt lgkmcnt(0)"
               : "=&s"(A) : "s"(p) : "memory");
  unsigned int m = A[0];
#pragma unroll
  for (int i = 1; i < 8; ++i) m = (A[i] < m) ? A[i] : m;
  return m;
}
static __device__ __forceinline__ unsigned int poll_min32(const unsigned int* p) {
  u32x16 A, B;
  asm volatile("s_dcache_inv\n\t"
               "s_load_dwordx16 %0, %1, 0x0\n\t"
               "s_waitcnt lgkmcnt(0)"
               : "=&s"(A) : "s"(p) : "memory");
  unsigned int m = A[0];
#pragma unroll
  for (int i = 1; i < 16; ++i) m = (A[i] < m) ? A[i] : m;
  asm volatile("s_load_dwordx16 %0, %1, 0x40\n\t"
               "s_waitcnt lgkmcnt(0)"
               : "=&s"(B) : "s"(p) : "memory");
#pragma unroll
  for (int i = 0; i < 16; ++i) m = (B[i] < m) ? B[i] : m;
  return m;
}

static __device__ __forceinline__ void wait_prod8(const unsigned int* tag8,
                                                  const unsigned int* tagBlane,
                                                  unsigned int tgt) {
  for (int spins = 0; spins < 4096; ++spins) {
    if (poll_min8(tag8) >= tgt) return;
  }
  for (;;) {
    const unsigned int v = __hip_atomic_load(tagBlane, __ATOMIC_RELAXED,
                                             __HIP_MEMORY_SCOPE_AGENT);
    if (__all((int)(v >= tgt))) return;
    __builtin_amdgcn_s_sleep(1);
  }
}
static __device__ __forceinline__ void wait_group32(const unsigned int* tagA,
                                                    const unsigned int* tagBlane,
                                                    unsigned int tgt) {
  for (int spins = 0; spins < 4096; ++spins) {
    if (poll_min32(tagA) >= tgt) return;
  }
  for (;;) {
    const unsigned int v = __hip_atomic_load(tagBlane, __ATOMIC_RELAXED,
                                             __HIP_MEMORY_SCOPE_AGENT);
    if (__all((int)(v >= tgt))) return;
    __builtin_amdgcn_s_sleep(1);
  }
}

__global__ __launch_bounds__(256, 1) void lstm_persistent(
    const int* __restrict__ x,
    const float* __restrict__ Wxg, const float* __restrict__ Whg,
    const float* __restrict__ Wxi, const float* __restrict__ Whi,
    const float* __restrict__ Wxf, const float* __restrict__ Whf,
    const float* __restrict__ Wxo, const float* __restrict__ Who,
    const float* __restrict__ Whp,
    const float* __restrict__ bg, const float* __restrict__ bi,
    const float* __restrict__ bf, const float* __restrict__ bo,
    const float* __restrict__ bp,
    float* __restrict__ out)
{
  const int bid = blockIdx.x;
  const int g = bid & 7;
  const int w = bid >> 3;
  const int tid = threadIdx.x;
  const int wave = tid >> 6;
  const int lane = tid & 63;
  const int lane15 = lane & 15;
  const int lanehi = lane >> 4;

  __shared__ __align__(16) float part[2][4][16][16][4]; // [pb][wv][row][col][gate] 32KB
  __shared__ int lds_x[16][TT];                         // 16KB
  __shared__ unsigned int lds_ctr;

  if (tid == 0) lds_ctr = 0u;
  for (int i = tid; i < 16 * TT; i += 256)
    ((int*)lds_x)[i] = x[g * 16 * TT + i];

  // ---- one-time: W_h fragments, 2-plane bf16 split, this wave's 4 k-steps ----
  const float* Whs[4] = {Whg, Whi, Whf, Who};
  const int bcol = (w << 4) + lane15;
  short8 wf[4][4][2];
#pragma unroll
  for (int gate = 0; gate < 4; ++gate) {
    const float* Wh = Whs[gate];
#pragma unroll
    for (int ksl = 0; ksl < 4; ++ksl) {
      const int ksg = (wave << 2) + ksl;
      short8 s0, s1;
#pragma unroll
      for (int e = 0; e < 8; ++e) {
        float v = Wh[(ksg * 32 + lanehi * 8 + e) * HDIM + bcol];
        unsigned short a = f32_to_bf16(v);
        unsigned short b = f32_to_bf16(v - bf16_to_f32(a));
        s0[e] = (short)a; s1[e] = (short)b;
      }
      wf[gate][ksl][0] = s0; wf[gate][ksl][1] = s1;
    }
  }
  __syncthreads();   // lds_x + lds_ctr ready

  // ---- elementwise mapping ----
  const int brow = tid >> 4;
  const int jl = tid & 15;
  const int j = (w << 4) + jl;
  const float bgv = bg[j], biv = bi[j], bfv = bf[j], bov = bo[j];
  // u32 index within a plane for h cols (j,j+1), row brow (even-j stores)
  const int woff32 = ((j >> 5) << 8) + ((((j >> 3) & 3) << 4) + brow) * 4 + ((j & 7) >> 1);
  const unsigned int voff = ((unsigned)wave << 12) + ((unsigned)lane << 4);

  const unsigned int* tagA = sgpr_ptr(g_sync + (g << 5));
  const unsigned int* tag8 = sgpr_ptr(g_sync + (g << 5) + (wave << 3));
  const unsigned int* tagBlane =
      g_sync + TAGB_OFF + ((unsigned)(g * 32 + (lane & 31)) << 4);
  unsigned int* myA = g_sync + (g << 5) + w;
  unsigned int* myB = g_sync + TAGB_OFF + ((unsigned)(g * 32 + w) << 4);

  float creg = 0.0f;

  for (int t = 0; t < NSTEPS; ++t) {
    // x-gather issued early (flies during the poll)
    const int idx = lds_x[brow][t];
    const float xgv = Wxg[idx * HDIM + j];
    const float xiv = Wxi[idx * HDIM + j];
    const float xfv = Wxf[idx * HDIM + j];
    const float xov = Wxo[idx * HDIM + j];

    f32x4 accA[4] = {{0.f,0.f,0.f,0.f},{0.f,0.f,0.f,0.f},
                     {0.f,0.f,0.f,0.f},{0.f,0.f,0.f,0.f}};
    f32x4 accB[4] = {{0.f,0.f,0.f,0.f},{0.f,0.f,0.f,0.f},
                     {0.f,0.f,0.f,0.f},{0.f,0.f,0.f,0.f}};
    if (t > 0) {
      wait_prod8(tag8, tagBlane, (unsigned int)t);   // only MY 8 producers
      // data loads: plane-separated, one voffset + immediate offsets
      const char* p0 = (const char*)(g_hbuf +
          ((size_t)((t & 3) * NGROUPS + g)) * PGW) + voff;
      short8 a0[4], a1[4];
#pragma unroll
      for (int ksl = 0; ksl < 4; ++ksl) {
        a0[ksl] = *(const short8*)(p0 + ksl * 1024);
        a1[ksl] = *(const short8*)(p0 + PLANE_W * 4 + ksl * 1024);
      }
      // 8 independent 6-deep MFMA chains (gate x half)
#pragma unroll
      for (int ksl = 0; ksl < 2; ++ksl) {
#pragma unroll
        for (int gate = 0; gate < 4; ++gate) {
          accA[gate] = __builtin_amdgcn_mfma_f32_16x16x32_bf16(a0[ksl], wf[gate][ksl][0], accA[gate], 0, 0, 0);
          accA[gate] = __builtin_amdgcn_mfma_f32_16x16x32_bf16(a0[ksl], wf[gate][ksl][1], accA[gate], 0, 0, 0);
          accA[gate] = __builtin_amdgcn_mfma_f32_16x16x32_bf16(a1[ksl], wf[gate][ksl][0], accA[gate], 0, 0, 0);
        }
      }
#pragma unroll
      for (int ksl = 2; ksl < 4; ++ksl) {
#pragma unroll
        for (int gate = 0; gate < 4; ++gate) {
          accB[gate] = __builtin_amdgcn_mfma_f32_16x16x32_bf16(a0[ksl], wf[gate][ksl][0], accB[gate], 0, 0, 0);
          accB[gate] = __builtin_amdgcn_mfma_f32_16x16x32_bf16(a0[ksl], wf[gate][ksl][1], accB[gate], 0, 0, 0);
          accB[gate] = __builtin_amdgcn_mfma_f32_16x16x32_bf16(a1[ksl], wf[gate][ksl][0], accB[gate], 0, 0, 0);
        }
      }
    }
    {
      const int crow = lanehi << 2;   // C/D: row=(lane>>4)*4+r, col=lane&15
      const int pb = t & 1;
#pragma unroll
      for (int r = 0; r < 4; ++r) {
        f32x4 vr;
#pragma unroll
        for (int gate = 0; gate < 4; ++gate)
          vr[gate] = accA[gate][r] + accB[gate][r];
        *(f32x4*)&part[pb][wave][crow + r][lane15][0] = vr;   // ds_write_b128
      }
    }
    __syncthreads();   // the ONE barrier per step

    const int pb = t & 1;
    const f32x4 s0 = *(const f32x4*)&part[pb][0][brow][jl][0];  // ds_read_b128
    const f32x4 s1 = *(const f32x4*)&part[pb][1][brow][jl][0];
    const f32x4 s2 = *(const f32x4*)&part[pb][2][brow][jl][0];
    const f32x4 s3 = *(const f32x4*)&part[pb][3][brow][jl][0];
    const f32x4 pre = s0 + s1 + s2 + s3;
    const float pg = pre[0] + xgv + bgv;
    const float pi = pre[1] + xiv + biv;
    const float pf = pre[2] + xfv + bfv;
    const float po = pre[3] + xov + bov;
    const float gv = fast_tanh(pg);
    const float iv = fast_sigmoid(pi);
    const float fv = fast_sigmoid(pf);
    const float ov = fast_sigmoid(po);
    creg = gv * iv + creg * fv;
    const float hv = fast_tanh(creg) * ov;

    const unsigned short h0 = f32_to_bf16(hv);
    const unsigned short h1 = f32_to_bf16(hv - bf16_to_f32(h0));
    const unsigned int pa = (unsigned int)h0 | ((unsigned int)h1 << 16);
    const unsigned int na = (unsigned int)__shfl_xor((int)pa, 1);
    if (!(jl & 1)) {
      unsigned int* dst0 = g_hbuf +
          ((size_t)(((t + 1) & 3) * NGROUPS + g)) * PGW;
      const unsigned int w0 = (pa & 0xffffu) | ((na & 0xffffu) << 16);  // plane0
      const unsigned int w1 = (pa >> 16) | (na & 0xffff0000u);          // plane1
      dst0[woff32] = w0;
      dst0[PLANE_W + woff32] = w1;
    }
    asm volatile("s_waitcnt vmcnt(0)" ::: "memory");  // stores acked at L2
    if (lane == 0) {
      const unsigned int old = atomicAdd(&lds_ctr, 1u);
      if ((old & 3u) == 3u) {   // last of this WG's 4 waves for step t
        __hip_atomic_store(myA, (unsigned int)(t + 1), __ATOMIC_RELAXED,
                           __HIP_MEMORY_SCOPE_WORKGROUP);   // plain -> XCD L2
        __hip_atomic_store(myB, (unsigned int)(t + 1), __ATOMIC_RELAXED,
                           __HIP_MEMORY_SCOPE_AGENT);       // LLC fallback copy
      }
    }
  }

  // ---- epilogue: out = h^255 @ W_hp + b_p ----
  wait_group32(tagA, tagBlane, (unsigned int)NSTEPS);
  __syncthreads();
  {
    const unsigned int* src =
        g_hbuf + ((size_t)((NSTEPS & 3) * NGROUPS + g)) * PGW;
    const int bq = tid >> 4;
    const int q15 = tid & 15;
    const int cloc = q15 >> 2;
    const int ksl2 = q15 & 3;
    const int cc = (w << 2) + cloc;
    float sum = 0.0f;
    for (int k = ksl2 * 128; k < ksl2 * 128 + 128; k += 2) {
      const int pk = ((k >> 5) << 8) + ((((k >> 3) & 3) << 4) + bq) * 4 + ((k & 7) >> 1);
      const unsigned int w0 = src[pk];
      const unsigned int w1 = src[PLANE_W + pk];
      const float hk0 = bf16_to_f32((unsigned short)(w0 & 0xffffu)) +
                        bf16_to_f32((unsigned short)(w1 & 0xffffu));
      const float hk1 = bf16_to_f32((unsigned short)(w0 >> 16)) +
                        bf16_to_f32((unsigned short)(w1 >> 16));
      sum += hk0 * Whp[k * CDIM + cc] + hk1 * Whp[(k + 1) * CDIM + cc];
    }
    float* gb = &part[0][0][0][0][0];
    gb[tid] = sum;
    __syncthreads();
    if (ksl2 == 0) {
      const float res = gb[tid] + gb[tid + 1] + gb[tid + 2] + gb[tid + 3] + bp[cc];
      out[(g * 16 + bq) * CDIM + cc] = res;
    }
  }
}

extern "C" void kernel_launch(void* const* d_in, const int* in_sizes, int n_in,
                              void* d_out, int out_size, void* d_ws, size_t ws_size,
                              hipStream_t stream) {
  (void)in_sizes; (void)n_in; (void)out_size; (void)d_ws; (void)ws_size;
  const int* x = (const int*)d_in[0];
  const float* Wxg = (const float*)d_in[1];
  const float* Whg = (const float*)d_in[2];
  const float* Wxi = (const float*)d_in[3];
  const float* Whi = (const float*)d_in[4];
  const float* Wxf = (const float*)d_in[5];
  const float* Whf = (const float*)d_in[6];
  const float* Wxo = (const float*)d_in[7];
  const float* Who = (const float*)d_in[8];
  const float* Whp = (const float*)d_in[9];
  const float* bg = (const float*)d_in[10];
  const float* bi = (const float*)d_in[11];
  const float* bf = (const float*)d_in[12];
  const float* bo = (const float*)d_in[13];
  const float* bp = (const float*)d_in[14];
  float* out = (float*)d_out;

  void* sync_dev = nullptr;
  hipGetSymbolAddress(&sync_dev, HIP_SYMBOL(g_sync));
  hipMemsetAsync(sync_dev, 0,
                 sizeof(unsigned int) * (TAGB_OFF + NGROUPS * WGS_PER_GROUP * 16),
                 stream);

  lstm_persistent<<<dim3(256), dim3(256), 0, stream>>>(
      x, Wxg, Whg, Wxi, Whi, Wxf, Whf, Wxo, Who, Whp,
      bg, bi, bf, bo, bp, out);
}